// Round 2
// baseline (784.007 us; speedup 1.0000x reference)
//
#include <hip/hip_runtime.h>
#include <hip/hip_bf16.h>
#include <cstdint>
#include <cstddef>

#define E_EXPERTS 24
#define D_DIM 1024
#define F_DIM 2048

#define BM 128
#define BN 128
#define BK 64

typedef float f32x4 __attribute__((ext_vector_type(4)));
typedef short s16x8 __attribute__((ext_vector_type(8)));
typedef unsigned short u16x4 __attribute__((ext_vector_type(4)));

static __device__ __forceinline__ unsigned short f2bf(float f) {
    union { float f; unsigned u; } v; v.f = f;
    unsigned r = v.u + 0x7FFFu + ((v.u >> 16) & 1u);   // RNE
    return (unsigned short)(r >> 16);
}
static __device__ __forceinline__ float bf2f(unsigned short h) {
    union { unsigned u; float f; } v; v.u = (unsigned)h << 16;
    return v.f;
}

// async global->LDS, 16B per lane; LDS dest = wave-uniform base + lane*16
#define GLL16(g, l) __builtin_amdgcn_global_load_lds(                         \
    (const __attribute__((address_space(1))) unsigned int*)(g),               \
    (__attribute__((address_space(3))) unsigned int*)(l), 16, 0, 0)

// ---------------- x fp32 -> bf16 ----------------
__global__ __launch_bounds__(256) void k_cvt(const float* __restrict__ in,
                                             unsigned short* __restrict__ out, int n) {
    int i = (blockIdx.x * 256 + threadIdx.x) * 8;
    if (i >= n) return;
    f32x4 a = *(const f32x4*)(in + i);
    f32x4 b = *(const f32x4*)(in + i + 4);
    s16x8 p;
    p[0] = (short)f2bf(a.x); p[1] = (short)f2bf(a.y);
    p[2] = (short)f2bf(a.z); p[3] = (short)f2bf(a.w);
    p[4] = (short)f2bf(b.x); p[5] = (short)f2bf(b.y);
    p[6] = (short)f2bf(b.z); p[7] = (short)f2bf(b.w);
    *(s16x8*)(out + i) = p;
}

// ---------------- transpose + convert: in[R][C] fp32 -> out[C][R] bf16 ----------------
__global__ __launch_bounds__(256) void k_tconv(const float* __restrict__ in,
                                               unsigned short* __restrict__ out,
                                               int R, int C) {
    in  += (size_t)blockIdx.z * R * C;
    out += (size_t)blockIdx.z * R * C;
    __shared__ float tl[32][33];
    const int rb = blockIdx.y * 32, cb = blockIdx.x * 32;
    const int r = threadIdx.x >> 3, c4 = (threadIdx.x & 7) * 4;
    f32x4 v = *(const f32x4*)(in + (size_t)(rb + r) * C + cb + c4);
    tl[r][c4 + 0] = v.x; tl[r][c4 + 1] = v.y;
    tl[r][c4 + 2] = v.z; tl[r][c4 + 3] = v.w;
    __syncthreads();
    u16x4 o;
    o[0] = f2bf(tl[c4 + 0][r]); o[1] = f2bf(tl[c4 + 1][r]);
    o[2] = f2bf(tl[c4 + 2][r]); o[3] = f2bf(tl[c4 + 3][r]);
    *(u16x4*)(out + (size_t)(cb + r) * R + rb + c4) = o;
}

// ---------------- gate + top-3 (one wave per token) ----------------
__global__ __launch_bounds__(256) void k_gate(const float* __restrict__ x,
                                              const float* __restrict__ gw,
                                              int* __restrict__ top3, int T) {
    int wave = (blockIdx.x * 256 + threadIdx.x) >> 6;
    int lane = threadIdx.x & 63;
    if (wave >= T) return;
    const float* xr = x + (size_t)wave * D_DIM;
    f32x4 xv[4];
#pragma unroll
    for (int i = 0; i < 4; ++i) xv[i] = *(const f32x4*)(xr + i * 256 + lane * 4);
    float v0 = -1e30f, v1 = -1e30f, v2 = -1e30f;
    int i0 = 0, i1 = 0, i2 = 0;
    for (int e = 0; e < E_EXPERTS; ++e) {
        const float* gr = gw + (size_t)e * D_DIM;
        float d = 0.f;
#pragma unroll
        for (int i = 0; i < 4; ++i) {
            f32x4 g = *(const f32x4*)(gr + i * 256 + lane * 4);
            d += xv[i].x * g.x + xv[i].y * g.y + xv[i].z * g.z + xv[i].w * g.w;
        }
#pragma unroll
        for (int s = 32; s > 0; s >>= 1) d += __shfl_xor(d, s, 64);
        if (d > v0)      { v2 = v1; i2 = i1; v1 = v0; i1 = i0; v0 = d; i0 = e; }
        else if (d > v1) { v2 = v1; i2 = i1; v1 = d;  i1 = e; }
        else if (d > v2) { v2 = d;  i2 = e; }
    }
    if (lane == 0) {
        top3[wave * 3 + 0] = i0;
        top3[wave * 3 + 1] = i1;
        top3[wave * 3 + 2] = i2;
    }
}

// ---------------- count + exclusive prefix (single block) ----------------
__global__ __launch_bounds__(256) void k_count(const int* __restrict__ top3,
                                               int* __restrict__ offs,
                                               int* __restrict__ cnt, int T) {
    __shared__ int lc[E_EXPERTS];
    int t = threadIdx.x;
    if (t < E_EXPERTS) lc[t] = 0;
    __syncthreads();
    for (int i = t; i < T * 3; i += 256) atomicAdd(&lc[top3[i]], 1);
    __syncthreads();
    if (t == 0) {
        int acc = 0;
        for (int e = 0; e < E_EXPERTS; ++e) { offs[e] = acc; acc += lc[e]; }
        offs[E_EXPERTS] = acc;
    }
    if (t < E_EXPERTS) cnt[t] = 0;
}

// ---------------- fill routing lists (block-local reservation) ----------------
__global__ __launch_bounds__(256) void k_fill(const int* __restrict__ top3,
                                              const int* __restrict__ offs,
                                              int* __restrict__ cnt,
                                              int* __restrict__ list,
                                              int* __restrict__ tslot, int T) {
    __shared__ int lc[E_EXPERTS], lbase[E_EXPERTS];
    int t = threadIdx.x;
    if (t < E_EXPERTS) lc[t] = 0;
    __syncthreads();
    int tok = blockIdx.x * 256 + t;
    int e[3], li[3];
    if (tok < T) {
#pragma unroll
        for (int k = 0; k < 3; ++k) {
            e[k] = top3[tok * 3 + k];
            li[k] = atomicAdd(&lc[e[k]], 1);
        }
    }
    __syncthreads();
    if (t < E_EXPERTS) lbase[t] = atomicAdd(&cnt[t], lc[t]);
    __syncthreads();
    if (tok < T) {
#pragma unroll
        for (int k = 0; k < 3; ++k) {
            int slot = offs[e[k]] + lbase[e[k]] + li[k];
            list[slot] = tok;
            tslot[tok * 3 + k] = slot;
        }
    }
}

// ---------------- grouped GEMM1: H = relu(Xbf_e @ W1T^T + b1[e]) ----------------
// A: gathered bf16 token rows (global_load_lds, per-lane gather addresses)
// B: W1T [E][F][D] bf16 rows (K-contiguous)
__global__ __launch_bounds__(256) void k_gemm1(const unsigned short* __restrict__ xbf,
                                               const unsigned short* __restrict__ w1t,
                                               const float* __restrict__ b1,
                                               const int* __restrict__ offs,
                                               const int* __restrict__ list,
                                               unsigned short* __restrict__ H) {
    const int e = blockIdx.z, mtile = blockIdx.y, ntile = blockIdx.x;
    const int offE = offs[e], cntE = offs[e + 1] - offE;
    if (mtile * BM >= cntE) return;
    __shared__ unsigned short Asl[BM][BK];
    __shared__ unsigned short Bsl[BN][BK];
    const int tid = threadIdx.x, lane = tid & 63, w = tid >> 6;
    const int wm = w >> 1, wn = w & 1;
    const int l8 = lane >> 3, l7 = lane & 7;

    size_t abase[4], bbase[4];
#pragma unroll
    for (int i = 0; i < 4; ++i) {
        int r = w * 32 + i * 8 + l8;
        int arow = mtile * BM + r;
        int tok = (arow < cntE) ? list[offE + arow] : list[offE];
        abase[i] = (size_t)tok * D_DIM + l7 * 8;
        int n = ntile * BN + w * 32 + i * 8 + l8;
        bbase[i] = ((size_t)e * F_DIM + n) * D_DIM + l7 * 8;
    }

    f32x4 acc[4][4];
#pragma unroll
    for (int i = 0; i < 4; ++i)
#pragma unroll
        for (int j = 0; j < 4; ++j) acc[i][j] = (f32x4){0.f, 0.f, 0.f, 0.f};

    for (int kt = 0; kt < D_DIM / BK; ++kt) {
        const int kb = kt * BK;
#pragma unroll
        for (int i = 0; i < 4; ++i)
            GLL16(xbf + abase[i] + kb, &Asl[w * 32 + i * 8][0]);
#pragma unroll
        for (int i = 0; i < 4; ++i)
            GLL16(w1t + bbase[i] + kb, &Bsl[w * 32 + i * 8][0]);
        __syncthreads();
#pragma unroll
        for (int kk = 0; kk < 2; ++kk) {
            s16x8 fa[4], fb[4];
            const int k0 = kk * 32 + (lane >> 4) * 8;
#pragma unroll
            for (int mi = 0; mi < 4; ++mi)
                fa[mi] = *(const s16x8*)&Asl[wm * 64 + mi * 16 + (lane & 15)][k0];
#pragma unroll
            for (int ni = 0; ni < 4; ++ni)
                fb[ni] = *(const s16x8*)&Bsl[wn * 64 + ni * 16 + (lane & 15)][k0];
#pragma unroll
            for (int mi = 0; mi < 4; ++mi)
#pragma unroll
                for (int ni = 0; ni < 4; ++ni)
                    acc[mi][ni] = __builtin_amdgcn_mfma_f32_16x16x32_bf16(
                        fa[mi], fb[ni], acc[mi][ni], 0, 0, 0);
        }
        __syncthreads();
    }
    const float* bias = b1 + (size_t)e * F_DIM;
#pragma unroll
    for (int ni = 0; ni < 4; ++ni) {
        int c = ntile * BN + wn * 64 + ni * 16 + (lane & 15);
        float bv = bias[c];
#pragma unroll
        for (int mi = 0; mi < 4; ++mi) {
            int rl = wm * 64 + mi * 16 + ((lane >> 4) << 2);
#pragma unroll
            for (int i = 0; i < 4; ++i) {
                int rowe = mtile * BM + rl + i;
                if (rowe < cntE) {
                    float h = acc[mi][ni][i] + bv;
                    h = h > 0.f ? h : 0.f;
                    H[(size_t)(offE + rowe) * F_DIM + c] = f2bf(h);
                }
            }
        }
    }
}

// ---------------- grouped GEMM2: Y = H_e @ W2T^T + b2[e] (bf16 out) ----------------
__global__ __launch_bounds__(256) void k_gemm2(const unsigned short* __restrict__ H,
                                               const unsigned short* __restrict__ w2t,
                                               const float* __restrict__ b2,
                                               const int* __restrict__ offs,
                                               unsigned short* __restrict__ Y) {
    const int e = blockIdx.z, mtile = blockIdx.y, ntile = blockIdx.x;
    const int offE = offs[e], cntE = offs[e + 1] - offE;
    if (mtile * BM >= cntE) return;
    __shared__ unsigned short Asl[BM][BK];
    __shared__ unsigned short Bsl[BN][BK];
    const int tid = threadIdx.x, lane = tid & 63, w = tid >> 6;
    const int wm = w >> 1, wn = w & 1;
    const int l8 = lane >> 3, l7 = lane & 7;

    size_t abase[4], bbase[4];
#pragma unroll
    for (int i = 0; i < 4; ++i) {
        int r = w * 32 + i * 8 + l8;
        abase[i] = (size_t)(offE + mtile * BM + r) * F_DIM + l7 * 8;  // H row-padded
        int n = ntile * BN + w * 32 + i * 8 + l8;
        bbase[i] = ((size_t)e * D_DIM + n) * F_DIM + l7 * 8;
    }

    f32x4 acc[4][4];
#pragma unroll
    for (int i = 0; i < 4; ++i)
#pragma unroll
        for (int j = 0; j < 4; ++j) acc[i][j] = (f32x4){0.f, 0.f, 0.f, 0.f};

    for (int kt = 0; kt < F_DIM / BK; ++kt) {
        const int kb = kt * BK;
#pragma unroll
        for (int i = 0; i < 4; ++i)
            GLL16(H + abase[i] + kb, &Asl[w * 32 + i * 8][0]);
#pragma unroll
        for (int i = 0; i < 4; ++i)
            GLL16(w2t + bbase[i] + kb, &Bsl[w * 32 + i * 8][0]);
        __syncthreads();
#pragma unroll
        for (int kk = 0; kk < 2; ++kk) {
            s16x8 fa[4], fb[4];
            const int k0 = kk * 32 + (lane >> 4) * 8;
#pragma unroll
            for (int mi = 0; mi < 4; ++mi)
                fa[mi] = *(const s16x8*)&Asl[wm * 64 + mi * 16 + (lane & 15)][k0];
#pragma unroll
            for (int ni = 0; ni < 4; ++ni)
                fb[ni] = *(const s16x8*)&Bsl[wn * 64 + ni * 16 + (lane & 15)][k0];
#pragma unroll
            for (int mi = 0; mi < 4; ++mi)
#pragma unroll
                for (int ni = 0; ni < 4; ++ni)
                    acc[mi][ni] = __builtin_amdgcn_mfma_f32_16x16x32_bf16(
                        fa[mi], fb[ni], acc[mi][ni], 0, 0, 0);
        }
        __syncthreads();
    }
    const float* bias = b2 + (size_t)e * D_DIM;
#pragma unroll
    for (int ni = 0; ni < 4; ++ni) {
        int c = ntile * BN + wn * 64 + ni * 16 + (lane & 15);
        float bv = bias[c];
#pragma unroll
        for (int mi = 0; mi < 4; ++mi) {
            int rl = wm * 64 + mi * 16 + ((lane >> 4) << 2);
#pragma unroll
            for (int i = 0; i < 4; ++i) {
                int rowe = mtile * BM + rl + i;
                if (rowe < cntE)
                    Y[(size_t)(offE + rowe) * D_DIM + c] = f2bf(acc[mi][ni][i] + bv);
            }
        }
    }
}

// ---------------- gather: out[t] = sum_k eg[k] * Y[slot(t,k)] ----------------
__global__ __launch_bounds__(256) void k_gather(const unsigned short* __restrict__ Y,
                                                const int* __restrict__ tslot,
                                                float* __restrict__ out, int T) {
    int idx = blockIdx.x * 256 + threadIdx.x;
    int t = idx >> 8, d4 = (idx & 255) * 4;
    if (t >= T) return;
    const unsigned short* y0 = Y + (size_t)tslot[t * 3 + 0] * D_DIM + d4;
    const unsigned short* y1 = Y + (size_t)tslot[t * 3 + 1] * D_DIM + d4;
    const unsigned short* y2 = Y + (size_t)tslot[t * 3 + 2] * D_DIM + d4;
    u16x4 a = *(const u16x4*)y0, b = *(const u16x4*)y1, c = *(const u16x4*)y2;
    f32x4 o;
#pragma unroll
    for (int j = 0; j < 4; ++j)
        o[j] = bf2f(a[j]) * 0.5f + bf2f(b[j]) * (1.f / 3.f) + bf2f(c[j]) * (1.f / 6.f);
    *(f32x4*)(out + (size_t)t * D_DIM + d4) = o;
}

extern "C" void kernel_launch(void* const* d_in, const int* in_sizes, int n_in,
                              void* d_out, int out_size, void* d_ws, size_t ws_size,
                              hipStream_t stream) {
    const float* x  = (const float*)d_in[0];
    const float* gw = (const float*)d_in[1];
    const float* w1 = (const float*)d_in[2];
    const float* b1 = (const float*)d_in[3];
    const float* w2 = (const float*)d_in[4];
    const float* b2 = (const float*)d_in[5];
    float* out = (float*)d_out;
    const int T = in_sizes[0] / D_DIM;   // 4096

    char* ws = (char*)d_ws;
    int* offs  = (int*)ws;                       // E+1 ints
    int* cnt   = (int*)(ws + 128);
    int* top3  = (int*)(ws + 256);               // T*3
    int* tslot = (int*)(ws + 256 + (size_t)T * 3 * 4);
    int* list  = (int*)(ws + 256 + (size_t)T * 3 * 8);
    size_t off = (256 + (size_t)T * 3 * 12 + 4095) & ~(size_t)4095;

    unsigned short* xbf = (unsigned short*)(ws + off);
    off += (size_t)T * D_DIM * 2;                               // 8.4 MB
    unsigned short* H = (unsigned short*)(ws + off);
    off += ((size_t)T * 3 + BM) * F_DIM * 2;                    // 50.9 MB (+pad rows)
    unsigned short* Y = (unsigned short*)(ws + off);
    off += (size_t)T * 3 * D_DIM * 2;                           // 25.2 MB
    off = (off + 4095) & ~(size_t)4095;
    unsigned short* wt = (unsigned short*)(ws + off);           // 100.7 MB, shared W1T/W2T

    const int mt = (T + BM - 1) / BM;  // 32 max M-tiles per expert

    k_cvt<<<dim3((T * D_DIM) / (256 * 8)), 256, 0, stream>>>(x, xbf, T * D_DIM);
    k_gate<<<dim3((T * 64 + 255) / 256), 256, 0, stream>>>(x, gw, top3, T);
    k_count<<<1, 256, 0, stream>>>(top3, offs, cnt, T);
    k_fill<<<dim3((T + 255) / 256), 256, 0, stream>>>(top3, offs, cnt, list, tslot, T);

    // W1 [E][D][F] -> wt = W1T [E][F][D] bf16, then GEMM1
    k_tconv<<<dim3(F_DIM / 32, D_DIM / 32, E_EXPERTS), 256, 0, stream>>>(w1, wt, D_DIM, F_DIM);
    k_gemm1<<<dim3(F_DIM / BN, mt, E_EXPERTS), 256, 0, stream>>>(xbf, wt, b1, offs, list, H);

    // W2 [E][F][D] -> wt = W2T [E][D][F] bf16 (reuses buffer), then GEMM2
    k_tconv<<<dim3(D_DIM / 32, F_DIM / 32, E_EXPERTS), 256, 0, stream>>>(w2, wt, F_DIM, D_DIM);
    k_gemm2<<<dim3(D_DIM / BN, mt, E_EXPERTS), 256, 0, stream>>>(H, wt, b2, offs, Y);

    k_gather<<<dim3(T, 1, 1), 256, 0, stream>>>(Y, tslot, out, T);
}